// Round 8
// baseline (286.397 us; speedup 1.0000x reference)
//
#include <hip/hip_runtime.h>
#include <hip/hip_bf16.h>

// Contrastive loss: N=4096, V=2, D=256.  M=8192 view-major rows.
// loss = mean_i [ log sum_{j!=i} exp(l_ij/T) - l_{i,pos}/T ],  l = norm(A)@norm(B)^T.
// Round 8: m201-style 256x256 tile, 8 waves (2x4), wave tile 128x64, BK=64,
// 4 K-steps cover full K=256 -> single fused LSE epilogue after the loop.
// A-in-registers abandoned (rounds 4-7: arch-VGPR side caps at 128 with MFMA
// accumulators present -> unavoidable spill). acc[8][4]=128 regs on the
// accumulator side; VGPR side ~100. LDS 128KB A+B double-buffer, counted
// vmcnt(8), per-phase barriers + setprio (T3/T4/T5), XOR-involution swizzle.

#define N_SAMP 4096
#define DIM    256
#define M_ROWS 8192
#define TEMP   0.07f

using short8 = __attribute__((ext_vector_type(8))) short;
using f32x4  = __attribute__((ext_vector_type(4))) float;

#define GLDS(g, l) __builtin_amdgcn_global_load_lds( \
    (const __attribute__((address_space(1))) void*)(g), \
    (__attribute__((address_space(3))) void*)(l), 16, 0, 0)

// ---------------------------------------------------------------------------
// Normalize rows (view-major) -> bf16; zero S / PosSum / cnt.
// ---------------------------------------------------------------------------
__global__ __launch_bounds__(256) void norm_kernel(
    const float* __restrict__ A, const float* __restrict__ B,
    unsigned short* __restrict__ Ah, unsigned short* __restrict__ Bh,
    float* __restrict__ S, float* __restrict__ PosSum, int* __restrict__ cnt)
{
  int tid = threadIdx.x;
  if (blockIdx.x < 8)
    ((float4*)S)[blockIdx.x * 256 + tid] = (float4){0.f, 0.f, 0.f, 0.f};
  if (blockIdx.x == 8 && tid == 0) { PosSum[0] = 0.f; cnt[0] = 0; }

  int wave = tid >> 6, lane = tid & 63;
  int gw   = blockIdx.x * 4 + wave;          // 0 .. 2*M-1
  const float* src; unsigned short* dst; int m;
  if (gw < M_ROWS) { src = A; dst = Ah; m = gw; }
  else             { src = B; dst = Bh; m = gw - M_ROWS; }
  int n = m & (N_SAMP - 1);
  int v = m >> 12;
  const float4* in = (const float4*)(src + (size_t)(n * 2 + v) * DIM);
  float4 x = in[lane];
  float ss = x.x*x.x + x.y*x.y + x.z*x.z + x.w*x.w;
  #pragma unroll
  for (int d = 1; d < 64; d <<= 1) ss += __shfl_xor(ss, d);
  float scale = 1.0f / fmaxf(sqrtf(ss), 1e-12f);
  float vals[4] = {x.x*scale, x.y*scale, x.z*scale, x.w*scale};
  ushort4 o;
  unsigned short* op = (unsigned short*)&o;
  #pragma unroll
  for (int k = 0; k < 4; ++k) {              // f32 -> bf16 RNE
    unsigned int u = __float_as_uint(vals[k]);
    u += 0x7fffu + ((u >> 16) & 1u);
    op[k] = (unsigned short)(u >> 16);
  }
  *(ushort4*)(dst + (size_t)m * DIM + lane * 4) = o;
}

// ---------------------------------------------------------------------------
// 256x256-tile GEMM, full K per block, fused LSE epilogue + final reduction.
// 512 thr = 8 waves (2x4); wave tile 128x64; 1 block/CU (LDS 128KB).
// ---------------------------------------------------------------------------
__global__ __launch_bounds__(512, 2) void gemm_lse_kernel(
    const unsigned short* __restrict__ Ah, const unsigned short* __restrict__ Bh,
    float* __restrict__ S, float* __restrict__ PosSum, int* __restrict__ cnt,
    float* __restrict__ out)
{
  __shared__ alignas(16) char lds[2 * 65536];   // [buf]{A 32KB | B 32KB}
  __shared__ float redbuf[8];
  __shared__ int lastFlag;

  int tid  = threadIdx.x;
  int lane = tid & 63;
  int w    = tid >> 6;
  int wrow = w >> 2, wcol = w & 3;           // 2x4 wave grid; wave = 128x64
  int row0 = blockIdx.y * 256;
  int col0 = blockIdx.x * 256;

  // stage K-tile kt (A 256x64 + B 256x64, 64KB) into buffer buf.
  // 8 GLDS x 16B per thread; source chunk XOR-swizzled (involution w/ read).
  auto stage = [&](int kt, int buf) {
    char* dstA = lds + buf * 65536;
    char* dstB = dstA + 32768;
    const char* srcA = (const char*)Ah + kt * 128;
    const char* srcB = (const char*)Bh + kt * 128;
    #pragma unroll
    for (int s = 0; s < 4; ++s) {
      int f = s * 512 + tid;                 // 0..2047
      int r = f >> 3, cd = f & 7;            // row 0..255, chunk 0..7
      int cs = cd ^ (r & 7);
      GLDS(srcA + (size_t)(row0 + r) * 512 + cs * 16, dstA + f * 16);
    }
    #pragma unroll
    for (int s = 0; s < 4; ++s) {
      int f = s * 512 + tid;
      int r = f >> 3, cd = f & 7;
      int cs = cd ^ (r & 7);
      GLDS(srcB + (size_t)(col0 + r) * 512 + cs * 16, dstB + f * 16);
    }
  };
  stage(0, 0);

  f32x4 acc[8][4];                           // 128 accumulator regs
  #pragma unroll
  for (int i = 0; i < 8; ++i)
    #pragma unroll
    for (int j = 0; j < 4; ++j)
      acc[i][j] = (f32x4){0.f, 0.f, 0.f, 0.f};

  #pragma unroll 1
  for (int t = 0; t < 4; ++t) {
    if (t < 3) {
      stage(t + 1, (t & 1) ^ 1);
      asm volatile("s_waitcnt vmcnt(8)" ::: "memory");   // tile t ready; t+1 in flight
    } else {
      asm volatile("s_waitcnt vmcnt(0)" ::: "memory");
    }
    __builtin_amdgcn_s_barrier();

    const char* Acur = lds + (t & 1) * 65536;
    const char* Bcur = Acur + 32768;

    // 4 phases: (mh,nh) quadrants of the wave's 128x64 tile; A-subtile held
    // across the two nh phases of each mh.
    #pragma unroll
    for (int mh = 0; mh < 2; ++mh) {
      short8 a[4][2];
      #pragma unroll
      for (int fm = 0; fm < 4; ++fm) {
        int ar = wrow * 128 + (mh * 4 + fm) * 16 + (lane & 15);
        #pragma unroll
        for (int kk = 0; kk < 2; ++kk) {
          int ca = kk * 4 + (lane >> 4);
          a[fm][kk] = *(const short8*)(Acur + ar * 128 + ((ca ^ (ar & 7)) * 16));
        }
      }
      #pragma unroll
      for (int nh = 0; nh < 2; ++nh) {
        short8 b[2][2];
        #pragma unroll
        for (int fn = 0; fn < 2; ++fn) {
          int br = wcol * 64 + (nh * 2 + fn) * 16 + (lane & 15);
          #pragma unroll
          for (int kk = 0; kk < 2; ++kk) {
            int cb = kk * 4 + (lane >> 4);
            b[fn][kk] = *(const short8*)(Bcur + br * 128 + ((cb ^ (br & 7)) * 16));
          }
        }
        __builtin_amdgcn_s_setprio(1);
        #pragma unroll
        for (int kk = 0; kk < 2; ++kk)
          #pragma unroll
          for (int fm = 0; fm < 4; ++fm)
            #pragma unroll
            for (int fn = 0; fn < 2; ++fn)
              acc[mh * 4 + fm][nh * 2 + fn] = __builtin_amdgcn_mfma_f32_16x16x32_bf16(
                  a[fm][kk], b[fn][kk], acc[mh * 4 + fm][nh * 2 + fn], 0, 0, 0);
        __builtin_amdgcn_s_setprio(0);
        __builtin_amdgcn_s_barrier();        // phase fence
      }
    }
  }

  // ---- fused epilogue: exp-sum per row, positives, then global accumulate.
  const float KE = (float)(1.4426950408889634 / 0.07);  // log2(e)/T
  float ssum[8][4];
  #pragma unroll
  for (int i = 0; i < 8; ++i)
    #pragma unroll
    for (int r = 0; r < 4; ++r) ssum[i][r] = 0.f;
  float psum = 0.f;

  #pragma unroll
  for (int fm = 0; fm < 8; ++fm) {
    #pragma unroll
    for (int fn = 0; fn < 4; ++fn) {
      int gj = col0 + wcol * 64 + fn * 16 + (lane & 15);
      #pragma unroll
      for (int r = 0; r < 4; ++r) {
        int gi = row0 + wrow * 128 + fm * 16 + (lane >> 4) * 4 + r;
        float l = acc[fm][fn][r];
        float e = exp2f(l * KE);
        if (((gi ^ gj) & (N_SAMP - 1)) == 0) {
          if (gi == gj) e = 0.f;             // diagonal excluded
          else psum += l;                    // the one positive for row gi
        }
        ssum[fm][r] += e;
      }
    }
  }
  #pragma unroll
  for (int fm = 0; fm < 8; ++fm) {
    #pragma unroll
    for (int r = 0; r < 4; ++r) {
      float v = ssum[fm][r];
      v += __shfl_xor(v, 1);
      v += __shfl_xor(v, 2);
      v += __shfl_xor(v, 4);
      v += __shfl_xor(v, 8);
      if ((lane & 15) == 0) {
        int gi = row0 + wrow * 128 + fm * 16 + (lane >> 4) * 4 + r;
        atomicAdd(&S[gi], v);
      }
    }
  }
  float pv = psum;
  #pragma unroll
  for (int d = 1; d < 64; d <<= 1) pv += __shfl_xor(pv, d);
  if (lane == 0) redbuf[w] = pv;
  __syncthreads();
  if (tid == 0) {
    float tsum = 0.f;
    #pragma unroll
    for (int k = 0; k < 8; ++k) tsum += redbuf[k];
    atomicAdd(PosSum, tsum);
  }

  // ---- completion counter; last of 1024 blocks computes the loss.
  __threadfence();
  if (tid == 0) lastFlag = (atomicAdd(cnt, 1) == 1023);
  __syncthreads();
  if (lastFlag) {
    __threadfence();
    float part = 0.f;
    for (int i = tid; i < M_ROWS; i += 512)
      part += logf(atomicAdd(&S[i], 0.0f));  // coherent read
    #pragma unroll
    for (int d = 1; d < 64; d <<= 1) part += __shfl_xor(part, d);
    __syncthreads();                         // redbuf reuse
    if (lane == 0) redbuf[w] = part;
    __syncthreads();
    if (tid == 0) {
      float sl = 0.f;
      #pragma unroll
      for (int k = 0; k < 8; ++k) sl += redbuf[k];
      float ps = atomicAdd(PosSum, 0.0f);    // coherent read
      out[0] = sl / (float)M_ROWS - ps / ((float)M_ROWS * TEMP);
    }
  }
}

extern "C" void kernel_launch(void* const* d_in, const int* in_sizes, int n_in,
                              void* d_out, int out_size, void* d_ws, size_t ws_size,
                              hipStream_t stream)
{
  const float* A = (const float*)d_in[0];
  const float* B = (const float*)d_in[1];
  char* ws = (char*)d_ws;
  unsigned short* Ah = (unsigned short*)ws;                                  // 4 MB
  unsigned short* Bh = (unsigned short*)(ws + (size_t)M_ROWS * DIM * 2);     // 4 MB
  float* S      = (float*)(ws + 2 * (size_t)M_ROWS * DIM * 2);               // 32 KB
  float* PosSum = S + M_ROWS;
  int*   cnt    = (int*)(PosSum + 1);

  norm_kernel<<<dim3(2 * M_ROWS / 4), 256, 0, stream>>>(A, B, Ah, Bh, S, PosSum, cnt);
  gemm_lse_kernel<<<dim3(32, 32), 512, 0, stream>>>(Ah, Bh, S, PosSum, cnt, (float*)d_out);
}